// Round 9
// baseline (209.098 us; speedup 1.0000x reference)
//
#include <hip/hip_runtime.h>
#include <cfloat>
#include <cstdint>

#define BATCH 16
#define PRIORS 3000
#define NCLS 201
#define NLBL 200           // NCLS - 1
#define TOPN 100
#define SCORE_THR 0.02f
#define NMS_THR 0.45f

// filter: 256-thread blocks, 4 waves, 4 priors/wave, wave-segmented ballot
// compaction (no atomics/LDS/barriers). NEW in v9: per-candidate global
// histogram add (fire-and-forget) + per-segment max key.
#define FPPB 16                              // priors per block
#define FBLK ((PRIORS + FPPB - 1) / FPPB)    // 188 blocks/image
#define SEGW 64                              // slots per wave-segment
#define SEGS (FBLK * 4)                      // 752 segments/image
#define SLOTS (SEGS * SEGW)                  // 48128 slots/image
#define OVF_CAP 1024

// nms v9: histogram precomputed by filter; collect pass prefiltered by
// segmax; register bitonic sort of 256 keys on wave 0 (waves 1-15 decode
// concurrently); wave-batched scan with shuffle-broadcast accepts.
// key = (float_bits(prob)<<32) | (0xFFFFFFFF-oid), oid = p*200+(c-1);
// descending-key order == jnp.argmax order (score desc, first-index ties).
#define NMS_T 1024
#define NBINS 1024         // strata over (key>>48)-SB_BASE, natural range 0..733
#define CHUNK 256          // 100th accept sits at sorted rank ~105
#define SB_BASE 0x3CA3     // floatbits(0.02) >> 16

__device__ __forceinline__ int key_stratum(uint64_t k) {
    int s = (int)(k >> 48) - SB_BASE;
    return s < 0 ? 0 : (s > NBINS - 1 ? NBINS - 1 : s);
}

// ---------------------------------------------------------------------------
// Kernel B: softmax + filter, wave-segmented output + histogram + segmax.
// Softmax arithmetic identical to R2-R8 (bit-stable, absmax 0.0).
// ---------------------------------------------------------------------------
__global__ __launch_bounds__(256) void score_filter_kernel(
    const float* __restrict__ obj,      // [B][P][NCLS]
    int*         __restrict__ cnt,      // [B] overflow counters (memset 0)
    uint32_t*    __restrict__ hist,     // [B][NBINS] stratum counts (memset 0)
    uint64_t*    __restrict__ segmax,   // [B][SEGS] per-segment max key
    uint64_t*    __restrict__ seg,      // [B][SEGS][SEGW]
    uint64_t*    __restrict__ ovf)      // [B][OVF_CAP]
{
    const int b    = blockIdx.y;
    const int wave = threadIdx.x >> 6;
    const int lane = threadIdx.x & 63;
    const int segId = blockIdx.x * 4 + wave;
    uint64_t* myseg = seg + ((size_t)b * SEGS + segId) * SEGW;
    uint32_t* myhist = hist + (size_t)b * NBINS;

    int cursor = 0;
    uint64_t wmax = 0ull;
#pragma unroll
    for (int pp = 0; pp < 4; ++pp) {
        int p = blockIdx.x * FPPB + wave * 4 + pp;
        if (p < PRIORS) {                         // wave-uniform guard
            const float* x = obj + ((size_t)b * PRIORS + p) * NCLS;
            float v0 = x[lane];
            float v1 = x[lane + 64];
            float v2 = x[lane + 128];
            float v3 = (lane + 192 < NCLS) ? x[lane + 192] : -FLT_MAX;
            float mx = fmaxf(fmaxf(v0, v1), fmaxf(v2, v3));
            for (int d = 32; d > 0; d >>= 1) mx = fmaxf(mx, __shfl_xor(mx, d, 64));
            float e0 = expf(v0 - mx), e1 = expf(v1 - mx), e2 = expf(v2 - mx);
            float e3 = (lane + 192 < NCLS) ? expf(v3 - mx) : 0.0f;
            float se = e0 + e1 + e2 + e3;
            for (int d = 32; d > 0; d >>= 1) se += __shfl_xor(se, d, 64);
            float inv = 1.0f / se;
            float ev[4] = { e0, e1, e2, e3 };
#pragma unroll
            for (int k = 0; k < 4; ++k) {
                int c = lane + 64 * k;
                float prob = ev[k] * inv;
                bool pass = (c >= 1) && (c < NCLS) && (prob > SCORE_THR);
                uint64_t mask = __ballot(pass);
                if (pass) {
                    uint32_t oid = (uint32_t)(p * NLBL + (c - 1));
                    uint64_t key = ((uint64_t)__float_as_uint(prob) << 32)
                                 | (uint64_t)(0xFFFFFFFFu - oid);
                    wmax = key > wmax ? key : wmax;
                    atomicAdd(&myhist[key_stratum(key)], 1u);  // fire-and-forget
                    int idx = cursor + __popcll(mask & ((1ull << lane) - 1ull));
                    if (idx < SEGW) {
                        myseg[idx] = key;
                    } else {                      // exact overflow path (never taken)
                        int gi = atomicAdd(&cnt[b], 1);
                        if (gi < OVF_CAP) ovf[(size_t)b * OVF_CAP + gi] = key;
                    }
                }
                cursor += (int)__popcll(mask);
            }
        }
    }
    int cc = cursor < SEGW ? cursor : SEGW;
    if (lane >= cc) myseg[lane] = 0ull;           // zero tail; nms skips key==0
    // per-segment max key (includes overflow keys -- conservative, harmless)
    for (int d = 32; d > 0; d >>= 1) {
        uint64_t o = __shfl_xor((unsigned long long)wmax, d, 64);
        wmax = o > wmax ? o : wmax;
    }
    if (lane == 0) segmax[(size_t)b * SEGS + segId] = wmax;
}

// ---------------------------------------------------------------------------
// Fallback single-candidate scan step on wave 0 (overfull-stratum path only;
// never taken with this data). Bit-identical box/area/IoU expressions.
// ---------------------------------------------------------------------------
__device__ __forceinline__ int scan_step_w0(
    uint64_t key, int b, const float4* __restrict__ dbox, float ofb,
    float4* abox, float* aarea, int na, float* __restrict__ out, int lane)
{
    uint32_t oid = 0xFFFFFFFFu - (uint32_t)key;
    int p = (int)(oid / NLBL);
    int c = (int)(oid - (uint32_t)p * NLBL) + 1;
    float4 db = dbox[p];
    float lo = (float)c * ofb;
    float qx1 = db.x + lo, qy1 = db.y + lo;
    float qx2 = db.z + lo, qy2 = db.w + lo;
    float aq = (qx2 - qx1) * (qy2 - qy1);
    bool sup = false;
    for (int l = lane; l < na; l += 64) {
        float4 a = abox[l];
        float ix1 = fmaxf(qx1, a.x);
        float iy1 = fmaxf(qy1, a.y);
        float ix2 = fminf(qx2, a.z);
        float iy2 = fminf(qy2, a.w);
        float inter = fmaxf(ix2 - ix1, 0.0f) * fmaxf(iy2 - iy1, 0.0f);
        float iou = inter / (aq + aarea[l] - inter);   // NaN>thr==false, like jnp
        if (iou > NMS_THR) sup = true;
    }
    if (__ballot(sup) == 0ull) {
        if (lane == 0) {
            abox[na]  = make_float4(qx1, qy1, qx2, qy2);
            aarea[na] = aq;
            float* o = out + ((size_t)b * TOPN + na) * 6;
            o[0] = fminf(fmaxf(db.x, 0.0f), 1.0f);
            o[1] = fminf(fmaxf(db.y, 0.0f), 1.0f);
            o[2] = fminf(fmaxf(db.z, 0.0f), 1.0f);
            o[3] = fminf(fmaxf(db.w, 0.0f), 1.0f);
            o[4] = __uint_as_float((uint32_t)(key >> 32));
            o[5] = (float)c;
        }
        __threadfence_block();
        return na + 1;
    }
    return na;
}

// ---------------------------------------------------------------------------
// Kernel C (v9): one block per image.
//  - suffix counts from precomputed hist (4 KB load, no slot pass);
//  - collect pass prefiltered by segmax (skips ~2/3 of segments);
//  - wave 0: register bitonic sort of 256 keys || waves 1-15: decode;
//  - wave-batched scan, accepted box broadcast via SHUFFLES (accepted lane
//    writes abox/output itself) -- no LDS round-trip on the accept chain.
//  Accepted lane force-removed (matches .at[i].set(-1), robust to NaN IoU).
// ---------------------------------------------------------------------------
__global__ __launch_bounds__(NMS_T) void nms_kernel(
    const float*    __restrict__ deltas,  // [B][P][4]
    const float*    __restrict__ priors,  // [P][4]
    const int*      __restrict__ cnt,     // [B] overflow counts
    const uint32_t* __restrict__ hist,    // [B][NBINS]
    const uint64_t* __restrict__ segmax,  // [B][SEGS]
    const uint64_t* __restrict__ seg,     // [B][SLOTS]
    const uint64_t* __restrict__ ovf,     // [B][OVF_CAP]
    float*          __restrict__ out)     // [B][TOPN][6]
{
    __shared__ float4   dbox[PRIORS];     // 48 KB decoded boxes
    __shared__ int      sufx[NBINS];      // inclusive suffix counts
    __shared__ uint64_t smax[SEGS];       // per-segment max keys
    __shared__ uint64_t skey[CHUNK];      // collected chunk (<=256)
    __shared__ float4   abox[112];        // accepted offset boxes (<=100)
    __shared__ float    aarea[112];
    __shared__ uint64_t rk[NMS_T / 64];
    __shared__ float    wredF[NMS_T / 64];
    __shared__ int      wtotS[NMS_T / 64];
    __shared__ int      carryS[NMS_T / 64];
    __shared__ int cnt256S, loS, naS;
    __shared__ uint64_t fkS;

    const int b    = blockIdx.x;
    const int tid  = threadIdx.x;
    const int wave = tid >> 6;
    const int lane = tid & 63;
    const uint64_t* slots = seg + (size_t)b * SLOTS;
    int n_ovf = cnt[b]; if (n_ovf > OVF_CAP) n_ovf = OVF_CAP;
    const uint64_t* ovfp = ovf + (size_t)b * OVF_CAP;

    // ---- init: load hist + segmax (coalesced), zero state ----
    sufx[tid] = (int)hist[(size_t)b * NBINS + tid];   // NBINS == NMS_T
    if (tid < SEGS) smax[tid] = segmax[(size_t)b * SEGS + tid];
    if (tid == 0) naS = 0;
    if (lane == 0) wredF[wave] = -FLT_MAX;  // wave 0 never decodes
    __syncthreads();

    // ---- wave-parallel inclusive suffix sum over 1024 bins ----
    {
        int v = sufx[64 * wave + lane];
        int s = v;
        for (int d = 1; d < 64; d <<= 1) {
            int t = __shfl_down(s, d, 64);
            if (lane + d < 64) s += t;
        }
        if (lane == 0) wtotS[wave] = s;
        __syncthreads();
        if (wave == 0 && lane < NMS_T / 64) {
            int tv = wtotS[lane];
            int ts = tv;
            for (int d = 1; d < NMS_T / 64; d <<= 1) {
                int t = __shfl_down(ts, d, 64);
                if (lane + d < NMS_T / 64) ts += t;
            }
            carryS[lane] = ts - tv;
        }
        __syncthreads();
        sufx[64 * wave + lane] = s + carryS[wave];
    }

    // ---- chunk loop ----
    int curHi = NBINS;
    bool decoded = false;
    for (;;) {
        __syncthreads();
        int naCur = naS;
        int A = (curHi < NBINS) ? sufx[curHi] : 0;
        int remaining = sufx[0] - A;
        if (naCur >= TOPN || remaining <= 0 || curHi <= 0) break;
        int target = A + CHUNK;
        if (tid == 0) { loS = curHi; cnt256S = 0; }
        __syncthreads();
        if (tid < curHi) {
            if (sufx[tid] <= target && (tid == 0 || sufx[tid - 1] > target))
                loS = tid;
        }
        __syncthreads();
        int lo = loS;

        if (lo < curHi) {
            // ---- collect [lo, curHi), segmax-prefiltered (<=256 keys) ----
            for (int sgi = wave; sgi < SEGS; sgi += NMS_T / 64) {
                uint64_t sm = smax[sgi];                 // wave-uniform read
                if (sm != 0ull && key_stratum(sm) >= lo) {
                    uint64_t k = slots[(size_t)sgi * SEGW + lane];
                    if (k) {
                        int s = key_stratum(k);
                        if (s >= lo && s < curHi) skey[atomicAdd(&cnt256S, 1)] = k;
                    }
                }
            }
            for (int j = tid; j < n_ovf; j += NMS_T) {
                uint64_t k = ovfp[j];
                if (k) {
                    int s = key_stratum(k);
                    if (s >= lo && s < curHi) skey[atomicAdd(&cnt256S, 1)] = k;
                }
            }
            __syncthreads();
            if (tid >= cnt256S && tid < CHUNK) skey[tid] = 0ull;
            __syncthreads();

            if (wave == 0) {
                // ======== wave 0: register bitonic sort of 256 keys ========
                uint64_t K[4];
#pragma unroll
                for (int r = 0; r < 4; ++r) K[r] = skey[r * 64 + lane];
#pragma unroll
                for (int k2 = 2; k2 <= 256; k2 <<= 1) {
#pragma unroll
                    for (int j2 = k2 >> 1; j2 >= 64; j2 >>= 1) {   // reg stages
                        int j2r = j2 >> 6;
#pragma unroll
                        for (int r = 0; r < 4; ++r) {
                            if ((r & j2r) == 0) {
                                int rp = r | j2r;
                                bool up = ((((r << 6) + lane) & k2) == 0);
                                uint64_t a = K[r], bb = K[rp];
                                uint64_t mx = a > bb ? a : bb;
                                uint64_t mn = a > bb ? bb : a;
                                K[r]  = up ? mx : mn;
                                K[rp] = up ? mn : mx;
                            }
                        }
                    }
#pragma unroll
                    for (int j2 = ((k2 >> 1) < 32 ? (k2 >> 1) : 32); j2 >= 1; j2 >>= 1) {
#pragma unroll
                        for (int r = 0; r < 4; ++r) {           // shuffle stages
                            uint64_t o = __shfl_xor((unsigned long long)K[r], j2, 64);
                            bool up = ((((r << 6) + lane) & k2) == 0);
                            bool lower = ((lane & j2) == 0);
                            K[r] = (up == lower) ? (K[r] > o ? K[r] : o)
                                                 : (K[r] < o ? K[r] : o);
                        }
                    }
                }
                __syncthreads();   // join: decode done on waves 1-15
                // ======== wave-batched scan, shuffle-broadcast accepts ========
                float ofb;
                {
                    float v = (lane < NMS_T / 64) ? wredF[lane] : -FLT_MAX;
                    for (int d = 32; d > 0; d >>= 1) v = fmaxf(v, __shfl_xor(v, d, 64));
                    ofb = v + 1.0f;
                }
                int na = naS;
#pragma unroll
                for (int r = 0; r < 4; ++r) {
                    if (na >= TOPN) break;
                    uint64_t myk = K[r];
                    bool valid = (myk != 0ull);
                    uint32_t oid = 0xFFFFFFFFu - (uint32_t)myk;
                    int p = valid ? (int)(oid / NLBL) : 0;
                    int c = valid ? ((int)(oid - (uint32_t)p * NLBL) + 1) : 1;
                    float4 db = dbox[p];
                    float lof = (float)c * ofb;
                    float qx1 = db.x + lof, qy1 = db.y + lof;
                    float qx2 = db.z + lof, qy2 = db.w + lof;
                    float aq = (qx2 - qx1) * (qy2 - qy1);
                    // phase A: parallel test vs accepts from earlier batches
                    bool dead = false;
                    for (int l = 0; l < na; ++l) {
                        float4 a = abox[l];               // broadcast LDS read
                        float ix1 = fmaxf(qx1, a.x), iy1 = fmaxf(qy1, a.y);
                        float ix2 = fminf(qx2, a.z), iy2 = fminf(qy2, a.w);
                        float inter = fmaxf(ix2 - ix1, 0.0f) * fmaxf(iy2 - iy1, 0.0f);
                        float iou = inter / (aq + aarea[l] - inter);
                        if (iou > NMS_THR) dead = true;
                    }
                    // phase B: in-wave sequential resolve (all-register)
                    uint64_t alive = __ballot(valid && !dead);
                    while (alive != 0ull && na < TOPN) {
                        int j = __ffsll((unsigned long long)alive) - 1;
                        float ax1 = __shfl(qx1, j, 64);
                        float ay1 = __shfl(qy1, j, 64);
                        float ax2 = __shfl(qx2, j, 64);
                        float ay2 = __shfl(qy2, j, 64);
                        float aa  = __shfl(aq,  j, 64);
                        if (lane == j) {                  // accepted lane writes
                            abox[na]  = make_float4(qx1, qy1, qx2, qy2);
                            aarea[na] = aq;
                            float* o = out + ((size_t)b * TOPN + na) * 6;
                            o[0] = fminf(fmaxf(db.x, 0.0f), 1.0f);
                            o[1] = fminf(fmaxf(db.y, 0.0f), 1.0f);
                            o[2] = fminf(fmaxf(db.z, 0.0f), 1.0f);
                            o[3] = fminf(fmaxf(db.w, 0.0f), 1.0f);
                            o[4] = __uint_as_float((uint32_t)(myk >> 32));
                            o[5] = (float)c;
                        }
                        na++;
                        bool mine = ((alive >> lane) & 1ull) != 0ull;
                        bool drop = (lane == j);          // force-remove accepted
                        if (mine && !drop) {
                            float ix1 = fmaxf(qx1, ax1), iy1 = fmaxf(qy1, ay1);
                            float ix2 = fminf(qx2, ax2), iy2 = fminf(qy2, ay2);
                            float inter = fmaxf(ix2 - ix1, 0.0f) * fmaxf(iy2 - iy1, 0.0f);
                            float iou = inter / (aq + aa - inter);
                            if (iou > NMS_THR) drop = true;
                        }
                        alive = __ballot(mine && !drop);
                    }
                }
                if (lane == 0) naS = na;
            } else {
                // ======== waves 1-15: decode 3000 priors -> LDS dbox ========
                if (!decoded) {
                    int base0 = (wave - 1) * 200;
                    float lmax = -FLT_MAX;
                    for (int p = base0 + lane; p < base0 + 200; p += 64) {
                        float4 d4 = ((const float4*)deltas)[(size_t)b * PRIORS + p];
                        float4 pr = ((const float4*)priors)[p];
                        float cx = d4.x * 0.1f * pr.z + pr.x;
                        float cy = d4.y * 0.1f * pr.w + pr.y;
                        float w  = expf(d4.z * 0.2f) * pr.z;
                        float h  = expf(d4.w * 0.2f) * pr.w;
                        float x1 = cx - 0.5f * w, y1 = cy - 0.5f * h;
                        float x2 = cx + 0.5f * w, y2 = cy + 0.5f * h;
                        dbox[p] = make_float4(x1, y1, x2, y2);
                        lmax = fmaxf(lmax, fmaxf(fmaxf(x1, y1), fmaxf(x2, y2)));
                    }
                    for (int d = 32; d > 0; d >>= 1)
                        lmax = fmaxf(lmax, __shfl_xor(lmax, d, 64));
                    if (lane == 0) wredF[wave] = lmax;
                }
                __syncthreads();   // pairs with wave 0's post-sort barrier
            }
            decoded = true;
            curHi = lo;
        } else {
            // ------- overfull stratum fallback (never with this data) -------
            if (!decoded) {
                float lmax = -FLT_MAX;
                for (int p = tid; p < PRIORS; p += NMS_T) {
                    float4 d4 = ((const float4*)deltas)[(size_t)b * PRIORS + p];
                    float4 pr = ((const float4*)priors)[p];
                    float cx = d4.x * 0.1f * pr.z + pr.x;
                    float cy = d4.y * 0.1f * pr.w + pr.y;
                    float w  = expf(d4.z * 0.2f) * pr.z;
                    float h  = expf(d4.w * 0.2f) * pr.w;
                    float x1 = cx - 0.5f * w, y1 = cy - 0.5f * h;
                    float x2 = cx + 0.5f * w, y2 = cy + 0.5f * h;
                    dbox[p] = make_float4(x1, y1, x2, y2);
                    lmax = fmaxf(lmax, fmaxf(fmaxf(x1, y1), fmaxf(x2, y2)));
                }
                for (int d = 32; d > 0; d >>= 1)
                    lmax = fmaxf(lmax, __shfl_xor(lmax, d, 64));
                if (lane == 0) wredF[wave] = lmax;
                __syncthreads();
                decoded = true;
            }
            float ofb;
            {
                float v = (lane < NMS_T / 64) ? wredF[lane] : -FLT_MAX;
                for (int d = 32; d > 0; d >>= 1) v = fmaxf(v, __shfl_xor(v, d, 64));
                ofb = v + 1.0f;
            }
            int s = curHi - 1;
            uint64_t lastK = ~0ull;
            for (;;) {
                __syncthreads();
                if (naS >= TOPN) break;
                uint64_t bk = 0ull;
                for (int j = tid; j < SLOTS; j += NMS_T) {
                    uint64_t k = slots[j];
                    if (k && key_stratum(k) == s && k < lastK && k > bk) bk = k;
                }
                for (int j = tid; j < n_ovf; j += NMS_T) {
                    uint64_t k = ovfp[j];
                    if (k && key_stratum(k) == s && k < lastK && k > bk) bk = k;
                }
                for (int d = 32; d > 0; d >>= 1) {
                    uint64_t o = __shfl_xor((unsigned long long)bk, d, 64);
                    bk = (o > bk) ? o : bk;
                }
                if (lane == 0) rk[wave] = bk;
                __syncthreads();
                if (tid == 0) {
                    uint64_t fk = rk[0];
                    for (int w = 1; w < NMS_T / 64; ++w) fk = (rk[w] > fk) ? rk[w] : fk;
                    fkS = fk;
                }
                __syncthreads();
                uint64_t fk = fkS;
                if (fk == 0ull) break;
                if (wave == 0) {
                    int nal = naS;
                    nal = scan_step_w0(fk, b, dbox, ofb, abox, aarea, nal, out, lane);
                    if (lane == 0) naS = nal;
                }
                lastK = fk;
            }
            curHi = s;
        }
    }
    // ---- zero-fill rows naS..99 (harness poisons d_out) ----
    __syncthreads();
    int naF = naS;
    for (int idx = tid; idx < (TOPN - naF) * 6; idx += NMS_T)
        out[(size_t)b * TOPN * 6 + (size_t)naF * 6 + idx] = 0.0f;
}

// ---------------------------------------------------------------------------
extern "C" void kernel_launch(void* const* d_in, const int* in_sizes, int n_in,
                              void* d_out, int out_size, void* d_ws, size_t ws_size,
                              hipStream_t stream)
{
    const float* deltas = (const float*)d_in[0];
    const float* obj    = (const float*)d_in[1];
    const float* priors = (const float*)d_in[2];
    float* out = (float*)d_out;

    char* ws = (char*)d_ws;
    // [cnt 64B][hist 64KB] -- one contiguous memset region; rest is always
    // fully written by the filter before nms reads it (no memset needed).
    int*      cnt    = (int*)ws;
    uint32_t* hist   = (uint32_t*)(ws + 64);
    size_t    zBytes = 64 + (size_t)BATCH * NBINS * 4;          // 65600
    size_t    off    = (zBytes + 255) & ~(size_t)255;
    uint64_t* segmax = (uint64_t*)(ws + off);                   // B*SEGS*8 = 96 KB
    uint64_t* seg    = segmax + (size_t)BATCH * SEGS;           // B*SLOTS*8 = 6.2 MB
    uint64_t* ovf    = seg + (size_t)BATCH * SLOTS;             // B*OVF_CAP*8

    hipMemsetAsync(ws, 0, zBytes, stream);
    dim3 fg(FBLK, BATCH, 1);
    score_filter_kernel<<<fg, 256, 0, stream>>>(obj, cnt, hist, segmax, seg, ovf);
    nms_kernel<<<BATCH, NMS_T, 0, stream>>>(deltas, priors, cnt, hist, segmax,
                                            seg, ovf, out);
}

// Round 10
// 134.632 us; speedup vs baseline: 1.5531x; 1.5531x over previous
//
#include <hip/hip_runtime.h>
#include <cfloat>
#include <cstdint>

#define BATCH 16
#define PRIORS 3000
#define NCLS 201
#define NLBL 200           // NCLS - 1
#define TOPN 100
#define SCORE_THR 0.02f
#define NMS_THR 0.45f

// filter: 256-thread blocks, 4 waves, 4 priors/wave, wave-segmented ballot
// compaction (no atomics/LDS/barriers). v10: per-segment HOT region
// (prob > T0) replaces R9's contended global histogram (R9 lesson: skewed
// strata -> hot-address atomics -> filter 87 us). Interleaved 4-prior
// softmax for ILP (expressions per candidate unchanged -> bit-exact).
#define FPPB 16                              // priors per block
#define FBLK ((PRIORS + FPPB - 1) / FPPB)    // 188 blocks/image
#define SEGW 64                              // slots per wave-segment
#define SEGS (FBLK * 4)                      // 752 segments/image
#define SLOTS (SEGS * SEGW)                  // 48128 slots/image
#define HOTW 8                               // hot slots per segment
#define OVF_CAP 1024
#define T0 0.08f           // hot threshold: ~315 hot/image (in [105,512] w/ margin)

// nms v10: fast path = gather hot keys (strict descending prefix of the
// full key order), register-sort 512 on wave 0, wave-batched scan.
// Exact fallback (hist + chunk loop + overfull-stratum argmax) if hot
// count > 512 or accepts < 100 -- recomputes from scratch, identical rows.
// key = (float_bits(prob)<<32) | (0xFFFFFFFF-oid), oid = p*200+(c-1);
// descending-key order == jnp.argmax order (score desc, first-index ties).
#define NMS_T 1024
#define NBINS 1024         // strata over (key>>48)-SB_BASE (fallback only)
#define HCAP 512
#define SB_BASE 0x3CA3     // floatbits(0.02) >> 16

__device__ __forceinline__ int key_stratum(uint64_t k) {
    int s = (int)(k >> 48) - SB_BASE;
    return s < 0 ? 0 : (s > NBINS - 1 ? NBINS - 1 : s);
}

// ---------------------------------------------------------------------------
// Kernel B (v10): interleaved 4-prior softmax + wave-segmented seg/hot write.
// Per-candidate arithmetic identical to R2-R9 (bit-stable, absmax 0.0).
// ---------------------------------------------------------------------------
__global__ __launch_bounds__(256) void score_filter_kernel(
    const float* __restrict__ obj,      // [B][P][NCLS]
    int*         __restrict__ cnt,      // [B] seg-overflow counter (memset 0)
    int*         __restrict__ hcnt,     // [B] hot-overflow counter (memset 0)
    uint64_t*    __restrict__ seg,      // [B][SEGS][SEGW]  all candidates
    uint64_t*    __restrict__ hot,      // [B][SEGS][HOTW]  prob > T0 only
    uint64_t*    __restrict__ ovf,      // [B][OVF_CAP]
    uint64_t*    __restrict__ hovf)     // [B][OVF_CAP]
{
    const int b    = blockIdx.y;
    const int wave = threadIdx.x >> 6;
    const int lane = threadIdx.x & 63;
    const int segId = blockIdx.x * 4 + wave;
    uint64_t* myseg = seg + ((size_t)b * SEGS + segId) * SEGW;
    uint64_t* myhot = hot + ((size_t)b * SEGS + segId) * HOTW;
    const int pbase = blockIdx.x * FPPB + wave * 4;

    // ---- 16 loads up front (4 priors x 4 class-chunks): max MLP ----
    float v0[4], v1[4], v2[4], v3[4];
    bool pv[4];
#pragma unroll
    for (int pp = 0; pp < 4; ++pp) {
        int p = pbase + pp;
        pv[pp] = (p < PRIORS);
        const float* x = obj + ((size_t)b * PRIORS + (pv[pp] ? p : PRIORS - 1)) * NCLS;
        v0[pp] = x[lane];
        v1[pp] = x[lane + 64];
        v2[pp] = x[lane + 128];
        v3[pp] = (lane + 192 < NCLS) ? x[lane + 192] : -FLT_MAX;
    }
    // ---- 4 independent interleaved reduction trees ----
    float mx[4];
#pragma unroll
    for (int pp = 0; pp < 4; ++pp)
        mx[pp] = fmaxf(fmaxf(v0[pp], v1[pp]), fmaxf(v2[pp], v3[pp]));
    for (int d = 32; d > 0; d >>= 1) {
#pragma unroll
        for (int pp = 0; pp < 4; ++pp)
            mx[pp] = fmaxf(mx[pp], __shfl_xor(mx[pp], d, 64));
    }
    float e0[4], e1[4], e2[4], e3[4], se[4];
#pragma unroll
    for (int pp = 0; pp < 4; ++pp) {
        e0[pp] = expf(v0[pp] - mx[pp]);
        e1[pp] = expf(v1[pp] - mx[pp]);
        e2[pp] = expf(v2[pp] - mx[pp]);
        e3[pp] = (lane + 192 < NCLS) ? expf(v3[pp] - mx[pp]) : 0.0f;
        se[pp] = e0[pp] + e1[pp] + e2[pp] + e3[pp];
    }
    for (int d = 32; d > 0; d >>= 1) {
#pragma unroll
        for (int pp = 0; pp < 4; ++pp)
            se[pp] += __shfl_xor(se[pp], d, 64);
    }
    // ---- emit: seg (all) + hot (prob > T0), ballot-compacted ----
    int cursor = 0, hcur = 0;
#pragma unroll
    for (int pp = 0; pp < 4; ++pp) {
        float inv = 1.0f / se[pp];
        int p = pbase + pp;
        float ev[4] = { e0[pp], e1[pp], e2[pp], e3[pp] };
#pragma unroll
        for (int k = 0; k < 4; ++k) {
            int c = lane + 64 * k;
            float prob = ev[k] * inv;
            bool pass = pv[pp] && (c >= 1) && (c < NCLS) && (prob > SCORE_THR);
            uint64_t mask = __ballot(pass);
            bool hotp = pass && (prob > T0);
            uint64_t hmask = __ballot(hotp);
            if (pass) {
                uint32_t oid = (uint32_t)(p * NLBL + (c - 1));
                uint64_t key = ((uint64_t)__float_as_uint(prob) << 32)
                             | (uint64_t)(0xFFFFFFFFu - oid);
                int idx = cursor + __popcll(mask & ((1ull << lane) - 1ull));
                if (idx < SEGW) {
                    myseg[idx] = key;
                } else {                       // exact seg overflow (never taken)
                    int gi = atomicAdd(&cnt[b], 1);
                    if (gi < OVF_CAP) ovf[(size_t)b * OVF_CAP + gi] = key;
                }
                if (hotp) {
                    int hidx = hcur + __popcll(hmask & ((1ull << lane) - 1ull));
                    if (hidx < HOTW) {
                        myhot[hidx] = key;
                    } else {                   // exact hot overflow (never taken)
                        int gi = atomicAdd(&hcnt[b], 1);
                        if (gi < OVF_CAP) hovf[(size_t)b * OVF_CAP + gi] = key;
                    }
                }
            }
            cursor += (int)__popcll(mask);
            hcur   += (int)__popcll(hmask);
        }
    }
    if (lane >= (cursor < SEGW ? cursor : SEGW)) myseg[lane] = 0ull;
    if (lane < HOTW && lane >= (hcur < HOTW ? hcur : HOTW)) myhot[lane] = 0ull;
}

// ---------------------------------------------------------------------------
// Wave-0 register bitonic sort of 512 u64 keys (8/lane), descending.
// shfl_xor for distance<=32, in-lane register exchange for 64/128/256.
// ---------------------------------------------------------------------------
__device__ __forceinline__ void sort512_desc(const uint64_t* skey,
                                             uint64_t K[8], int lane)
{
#pragma unroll
    for (int r = 0; r < 8; ++r) K[r] = skey[r * 64 + lane];
#pragma unroll
    for (int k2 = 2; k2 <= 512; k2 <<= 1) {
#pragma unroll
        for (int j2 = k2 >> 1; j2 >= 64; j2 >>= 1) {     // register stages
            int j2r = j2 >> 6;
#pragma unroll
            for (int r = 0; r < 8; ++r) {
                if ((r & j2r) == 0) {
                    int rp = r | j2r;
                    bool up = ((((r << 6) + lane) & k2) == 0);
                    uint64_t a = K[r], bb = K[rp];
                    uint64_t mxk = a > bb ? a : bb;
                    uint64_t mnk = a > bb ? bb : a;
                    K[r]  = up ? mxk : mnk;
                    K[rp] = up ? mnk : mxk;
                }
            }
        }
#pragma unroll
        for (int j2 = ((k2 >> 1) < 32 ? (k2 >> 1) : 32); j2 >= 1; j2 >>= 1) {
#pragma unroll
            for (int r = 0; r < 8; ++r) {                // shuffle stages
                uint64_t o = __shfl_xor((unsigned long long)K[r], j2, 64);
                bool up = ((((r << 6) + lane) & k2) == 0);
                bool lower = ((lane & j2) == 0);
                K[r] = (up == lower) ? (K[r] > o ? K[r] : o)
                                     : (K[r] < o ? K[r] : o);
            }
        }
    }
}

// ---------------------------------------------------------------------------
// Wave-0 batched scan over sorted K[8] (desc). Phase A: parallel IoU vs
// accepted list; phase B: in-wave sequential resolve, shuffle-broadcast
// accepts, accepted lane force-removed (matches .at[i].set(-1)).
// Box/area/IoU expressions bit-identical to the reference's bo/areas.
// ---------------------------------------------------------------------------
__device__ __forceinline__ int scan_sorted_w0(
    const uint64_t K[8], int b, const float4* __restrict__ dbox, float ofb,
    float4* abox, float* aarea, int na, float* __restrict__ out, int lane)
{
#pragma unroll
    for (int r = 0; r < 8; ++r) {
        if (na >= TOPN) break;
        uint64_t myk = K[r];
        bool valid = (myk != 0ull);
        uint32_t oid = 0xFFFFFFFFu - (uint32_t)myk;
        int p = valid ? (int)(oid / NLBL) : 0;
        int c = valid ? ((int)(oid - (uint32_t)p * NLBL) + 1) : 1;
        float4 db = dbox[p];
        float lof = (float)c * ofb;
        float qx1 = db.x + lof, qy1 = db.y + lof;
        float qx2 = db.z + lof, qy2 = db.w + lof;
        float aq = (qx2 - qx1) * (qy2 - qy1);
        bool dead = false;
        for (int l = 0; l < na; ++l) {
            float4 a = abox[l];                    // broadcast LDS read
            float ix1 = fmaxf(qx1, a.x), iy1 = fmaxf(qy1, a.y);
            float ix2 = fminf(qx2, a.z), iy2 = fminf(qy2, a.w);
            float inter = fmaxf(ix2 - ix1, 0.0f) * fmaxf(iy2 - iy1, 0.0f);
            float iou = inter / (aq + aarea[l] - inter);  // NaN>thr==false
            if (iou > NMS_THR) dead = true;
        }
        uint64_t alive = __ballot(valid && !dead);
        while (alive != 0ull && na < TOPN) {
            int j = __ffsll((unsigned long long)alive) - 1;
            float ax1 = __shfl(qx1, j, 64);
            float ay1 = __shfl(qy1, j, 64);
            float ax2 = __shfl(qx2, j, 64);
            float ay2 = __shfl(qy2, j, 64);
            float aa  = __shfl(aq,  j, 64);
            if (lane == j) {                       // accepted lane writes
                abox[na]  = make_float4(qx1, qy1, qx2, qy2);
                aarea[na] = aq;
                float* o = out + ((size_t)b * TOPN + na) * 6;
                o[0] = fminf(fmaxf(db.x, 0.0f), 1.0f);
                o[1] = fminf(fmaxf(db.y, 0.0f), 1.0f);
                o[2] = fminf(fmaxf(db.z, 0.0f), 1.0f);
                o[3] = fminf(fmaxf(db.w, 0.0f), 1.0f);
                o[4] = __uint_as_float((uint32_t)(myk >> 32));
                o[5] = (float)c;
            }
            na++;
            bool mine = ((alive >> lane) & 1ull) != 0ull;
            bool drop = (lane == j);               // force-remove accepted
            if (mine && !drop) {
                float ix1 = fmaxf(qx1, ax1), iy1 = fmaxf(qy1, ay1);
                float ix2 = fminf(qx2, ax2), iy2 = fminf(qy2, ay2);
                float inter = fmaxf(ix2 - ix1, 0.0f) * fmaxf(iy2 - iy1, 0.0f);
                float iou = inter / (aq + aa - inter);
                if (iou > NMS_THR) drop = true;
            }
            alive = __ballot(mine && !drop);
        }
    }
    return na;
}

// ---------------------------------------------------------------------------
// Fallback single-candidate scan step (overfull-stratum path; never taken).
// ---------------------------------------------------------------------------
__device__ __forceinline__ int scan_step_w0(
    uint64_t key, int b, const float4* __restrict__ dbox, float ofb,
    float4* abox, float* aarea, int na, float* __restrict__ out, int lane)
{
    uint32_t oid = 0xFFFFFFFFu - (uint32_t)key;
    int p = (int)(oid / NLBL);
    int c = (int)(oid - (uint32_t)p * NLBL) + 1;
    float4 db = dbox[p];
    float lo = (float)c * ofb;
    float qx1 = db.x + lo, qy1 = db.y + lo;
    float qx2 = db.z + lo, qy2 = db.w + lo;
    float aq = (qx2 - qx1) * (qy2 - qy1);
    bool sup = false;
    for (int l = lane; l < na; l += 64) {
        float4 a = abox[l];
        float ix1 = fmaxf(qx1, a.x), iy1 = fmaxf(qy1, a.y);
        float ix2 = fminf(qx2, a.z), iy2 = fminf(qy2, a.w);
        float inter = fmaxf(ix2 - ix1, 0.0f) * fmaxf(iy2 - iy1, 0.0f);
        float iou = inter / (aq + aarea[l] - inter);
        if (iou > NMS_THR) sup = true;
    }
    if (__ballot(sup) == 0ull) {
        if (lane == 0) {
            abox[na]  = make_float4(qx1, qy1, qx2, qy2);
            aarea[na] = aq;
            float* o = out + ((size_t)b * TOPN + na) * 6;
            o[0] = fminf(fmaxf(db.x, 0.0f), 1.0f);
            o[1] = fminf(fmaxf(db.y, 0.0f), 1.0f);
            o[2] = fminf(fmaxf(db.z, 0.0f), 1.0f);
            o[3] = fminf(fmaxf(db.w, 0.0f), 1.0f);
            o[4] = __uint_as_float((uint32_t)(key >> 32));
            o[5] = (float)c;
        }
        __threadfence_block();
        return na + 1;
    }
    return na;
}

// ---------------------------------------------------------------------------
// Kernel C (v10): one block per image.
// FAST PATH: gather hot keys (48 KB) -> wave 0 register-sorts 512 while
// waves 1-15 decode -> wave-batched scan. Hot set is a strict descending
// prefix of the full key order (hot prob > T0 >= non-hot prob).
// EXACT FALLBACK (hot>512 or accepts<100; never with this data): full
// decode + in-LDS histogram + suffix counts + 512-chunk loop + overfull-
// stratum argmax. Recomputes from na=0 -> identical rows rewritten.
// ---------------------------------------------------------------------------
__global__ __launch_bounds__(NMS_T) void nms_kernel(
    const float*    __restrict__ deltas,  // [B][P][4]
    const float*    __restrict__ priors,  // [P][4]
    const int*      __restrict__ cnt,     // [B] seg-overflow counts
    const int*      __restrict__ hcnt,    // [B] hot-overflow counts
    const uint64_t* __restrict__ seg,     // [B][SLOTS]
    const uint64_t* __restrict__ hot,     // [B][SEGS*HOTW]
    const uint64_t* __restrict__ ovf,     // [B][OVF_CAP]
    const uint64_t* __restrict__ hovf,    // [B][OVF_CAP]
    float*          __restrict__ out)     // [B][TOPN][6]
{
    __shared__ float4   dbox[PRIORS];     // 48 KB decoded boxes
    __shared__ int      sufx[NBINS];      // fallback suffix counts
    __shared__ uint64_t skey[HCAP];       // collected keys (<=512)
    __shared__ float4   abox[112];        // accepted offset boxes (<=100)
    __shared__ float    aarea[112];
    __shared__ uint64_t rk[NMS_T / 64];
    __shared__ float    wredF[NMS_T / 64];
    __shared__ int      wtotS[NMS_T / 64];
    __shared__ int      carryS[NMS_T / 64];
    __shared__ int cntC, loS, naS;
    __shared__ uint64_t fkS;

    const int b    = blockIdx.x;
    const int tid  = threadIdx.x;
    const int wave = tid >> 6;
    const int lane = tid & 63;
    const uint64_t* slots  = seg  + (size_t)b * SLOTS;
    const uint64_t* hslots = hot  + (size_t)b * SEGS * HOTW;
    int n_ovf  = cnt[b];  if (n_ovf  > OVF_CAP) n_ovf  = OVF_CAP;
    int n_hovf = hcnt[b]; if (n_hovf > OVF_CAP) n_hovf = OVF_CAP;
    const uint64_t* ovfp  = ovf  + (size_t)b * OVF_CAP;
    const uint64_t* hovfp = hovf + (size_t)b * OVF_CAP;

    if (tid == 0) { cntC = 0; naS = 0; }
    if (lane == 0) wredF[wave] = -FLT_MAX;
    __syncthreads();

    // ======== FAST PATH: collect hot keys (strict desc prefix) ========
    for (int j = tid; j < SEGS * HOTW; j += NMS_T) {
        uint64_t k = hslots[j];
        if (k) { int i = atomicAdd(&cntC, 1); if (i < HCAP) skey[i] = k; }
    }
    for (int j = tid; j < n_hovf; j += NMS_T) {
        uint64_t k = hovfp[j];
        if (k) { int i = atomicAdd(&cntC, 1); if (i < HCAP) skey[i] = k; }
    }
    __syncthreads();
    int hc = cntC;                          // uniform
    bool decoded = false;
    if (hc <= HCAP) {
        if (tid < HCAP && tid >= hc) skey[tid] = 0ull;
        __syncthreads();
        if (wave == 0) {
            uint64_t K[8];
            sort512_desc(skey, K, lane);
            __syncthreads();                // join: decode done on waves 1-15
            float ofb;
            {
                float v = (lane < NMS_T / 64) ? wredF[lane] : -FLT_MAX;
                for (int d = 32; d > 0; d >>= 1) v = fmaxf(v, __shfl_xor(v, d, 64));
                ofb = v + 1.0f;
            }
            int na = scan_sorted_w0(K, b, dbox, ofb, abox, aarea, 0, out, lane);
            if (lane == 0) naS = na;
        } else {
            // waves 1-15: decode 3000 priors -> LDS dbox (200 each)
            int base0 = (wave - 1) * 200;
            float lmax = -FLT_MAX;
            for (int p = base0 + lane; p < base0 + 200; p += 64) {
                float4 d4 = ((const float4*)deltas)[(size_t)b * PRIORS + p];
                float4 pr = ((const float4*)priors)[p];
                float cx = d4.x * 0.1f * pr.z + pr.x;
                float cy = d4.y * 0.1f * pr.w + pr.y;
                float w  = expf(d4.z * 0.2f) * pr.z;
                float h  = expf(d4.w * 0.2f) * pr.w;
                float x1 = cx - 0.5f * w, y1 = cy - 0.5f * h;
                float x2 = cx + 0.5f * w, y2 = cy + 0.5f * h;
                dbox[p] = make_float4(x1, y1, x2, y2);
                lmax = fmaxf(lmax, fmaxf(fmaxf(x1, y1), fmaxf(x2, y2)));
            }
            for (int d = 32; d > 0; d >>= 1)
                lmax = fmaxf(lmax, __shfl_xor(lmax, d, 64));
            if (lane == 0) wredF[wave] = lmax;
            __syncthreads();                // pairs with wave 0's post-sort barrier
        }
        decoded = true;
        __syncthreads();
    }

    // ======== EXACT FALLBACK (never with this data) ========
    if (naS < TOPN) {
        if (!decoded) {
            float lmax = -FLT_MAX;
            for (int p = tid; p < PRIORS; p += NMS_T) {
                float4 d4 = ((const float4*)deltas)[(size_t)b * PRIORS + p];
                float4 pr = ((const float4*)priors)[p];
                float cx = d4.x * 0.1f * pr.z + pr.x;
                float cy = d4.y * 0.1f * pr.w + pr.y;
                float w  = expf(d4.z * 0.2f) * pr.z;
                float h  = expf(d4.w * 0.2f) * pr.w;
                float x1 = cx - 0.5f * w, y1 = cy - 0.5f * h;
                float x2 = cx + 0.5f * w, y2 = cy + 0.5f * h;
                dbox[p] = make_float4(x1, y1, x2, y2);
                lmax = fmaxf(lmax, fmaxf(fmaxf(x1, y1), fmaxf(x2, y2)));
            }
            for (int d = 32; d > 0; d >>= 1)
                lmax = fmaxf(lmax, __shfl_xor(lmax, d, 64));
            if (lane == 0) wredF[wave] = lmax;
        }
        sufx[tid] = 0;
        if (tid == 0) naS = 0;              // restart: rows rewritten identically
        __syncthreads();
        // histogram over ALL candidates (seg + ovf)
        for (int j = tid; j < SLOTS; j += NMS_T) {
            uint64_t k = slots[j];
            if (k) atomicAdd(&sufx[key_stratum(k)], 1);
        }
        for (int j = tid; j < n_ovf; j += NMS_T) {
            uint64_t k = ovfp[j];
            if (k) atomicAdd(&sufx[key_stratum(k)], 1);
        }
        __syncthreads();
        // wave-parallel inclusive suffix sum
        {
            int v = sufx[64 * wave + lane];
            int s = v;
            for (int d = 1; d < 64; d <<= 1) {
                int t = __shfl_down(s, d, 64);
                if (lane + d < 64) s += t;
            }
            if (lane == 0) wtotS[wave] = s;
            __syncthreads();
            if (wave == 0 && lane < NMS_T / 64) {
                int tv = wtotS[lane];
                int ts = tv;
                for (int d = 1; d < NMS_T / 64; d <<= 1) {
                    int t = __shfl_down(ts, d, 64);
                    if (lane + d < NMS_T / 64) ts += t;
                }
                carryS[lane] = ts - tv;
            }
            __syncthreads();
            sufx[64 * wave + lane] = s + carryS[wave];
        }
        // chunk loop (chunks of HCAP=512)
        int curHi = NBINS;
        for (;;) {
            __syncthreads();
            int naCur = naS;
            int A = (curHi < NBINS) ? sufx[curHi] : 0;
            int remaining = sufx[0] - A;
            if (naCur >= TOPN || remaining <= 0 || curHi <= 0) break;
            int target = A + HCAP;
            if (tid == 0) { loS = curHi; cntC = 0; }
            __syncthreads();
            if (tid < curHi) {
                if (sufx[tid] <= target && (tid == 0 || sufx[tid - 1] > target))
                    loS = tid;
            }
            __syncthreads();
            int lo = loS;

            if (lo < curHi) {
                for (int j = tid; j < SLOTS; j += NMS_T) {
                    uint64_t k = slots[j];
                    if (k) {
                        int s = key_stratum(k);
                        if (s >= lo && s < curHi) {
                            int i = atomicAdd(&cntC, 1);
                            if (i < HCAP) skey[i] = k;   // <= HCAP by construction
                        }
                    }
                }
                for (int j = tid; j < n_ovf; j += NMS_T) {
                    uint64_t k = ovfp[j];
                    if (k) {
                        int s = key_stratum(k);
                        if (s >= lo && s < curHi) {
                            int i = atomicAdd(&cntC, 1);
                            if (i < HCAP) skey[i] = k;
                        }
                    }
                }
                __syncthreads();
                if (tid < HCAP && tid >= cntC) skey[tid] = 0ull;
                __syncthreads();
                if (wave == 0) {
                    uint64_t K[8];
                    sort512_desc(skey, K, lane);
                    float ofb;
                    {
                        float v = (lane < NMS_T / 64) ? wredF[lane] : -FLT_MAX;
                        for (int d = 32; d > 0; d >>= 1) v = fmaxf(v, __shfl_xor(v, d, 64));
                        ofb = v + 1.0f;
                    }
                    int na = scan_sorted_w0(K, b, dbox, ofb, abox, aarea, naS, out, lane);
                    if (lane == 0) naS = na;
                }
                curHi = lo;
            } else {
                // overfull stratum: exact extraction by repeated block argmax
                float ofbT;
                {
                    float v = (lane < NMS_T / 64) ? wredF[lane] : -FLT_MAX;
                    for (int d = 32; d > 0; d >>= 1) v = fmaxf(v, __shfl_xor(v, d, 64));
                    ofbT = v + 1.0f;
                }
                int s = curHi - 1;
                uint64_t lastK = ~0ull;
                for (;;) {
                    __syncthreads();
                    if (naS >= TOPN) break;
                    uint64_t bk = 0ull;
                    for (int j = tid; j < SLOTS; j += NMS_T) {
                        uint64_t k = slots[j];
                        if (k && key_stratum(k) == s && k < lastK && k > bk) bk = k;
                    }
                    for (int j = tid; j < n_ovf; j += NMS_T) {
                        uint64_t k = ovfp[j];
                        if (k && key_stratum(k) == s && k < lastK && k > bk) bk = k;
                    }
                    for (int d = 32; d > 0; d >>= 1) {
                        uint64_t o = __shfl_xor((unsigned long long)bk, d, 64);
                        bk = (o > bk) ? o : bk;
                    }
                    if (lane == 0) rk[wave] = bk;
                    __syncthreads();
                    if (tid == 0) {
                        uint64_t fk = rk[0];
                        for (int w = 1; w < NMS_T / 64; ++w) fk = (rk[w] > fk) ? rk[w] : fk;
                        fkS = fk;
                    }
                    __syncthreads();
                    uint64_t fk = fkS;
                    if (fk == 0ull) break;
                    if (wave == 0) {
                        int nal = naS;
                        nal = scan_step_w0(fk, b, dbox, ofbT, abox, aarea, nal, out, lane);
                        if (lane == 0) naS = nal;
                    }
                    lastK = fk;
                }
                curHi = s;
            }
        }
    }
    // ---- zero-fill rows naS..99 (harness poisons d_out) ----
    __syncthreads();
    int naF = naS;
    for (int idx = tid; idx < (TOPN - naF) * 6; idx += NMS_T)
        out[(size_t)b * TOPN * 6 + (size_t)naF * 6 + idx] = 0.0f;
}

// ---------------------------------------------------------------------------
extern "C" void kernel_launch(void* const* d_in, const int* in_sizes, int n_in,
                              void* d_out, int out_size, void* d_ws, size_t ws_size,
                              hipStream_t stream)
{
    const float* deltas = (const float*)d_in[0];
    const float* obj    = (const float*)d_in[1];
    const float* priors = (const float*)d_in[2];
    float* out = (float*)d_out;

    char* ws = (char*)d_ws;
    int*      cnt  = (int*)ws;                              // 64 B
    int*      hcnt = (int*)(ws + 64);                       // 64 B
    uint64_t* hotA = (uint64_t*)(ws + 256);                 // B*SEGS*HOTW*8 = 770 KB
    uint64_t* segA = hotA + (size_t)BATCH * SEGS * HOTW;    // B*SLOTS*8 = 6.2 MB
    uint64_t* ovfA = segA + (size_t)BATCH * SLOTS;          // 128 KB
    uint64_t* hovA = ovfA + (size_t)BATCH * OVF_CAP;        // 128 KB

    hipMemsetAsync(ws, 0, 128, stream);
    dim3 fg(FBLK, BATCH, 1);
    score_filter_kernel<<<fg, 256, 0, stream>>>(obj, cnt, hcnt, segA, hotA, ovfA, hovA);
    nms_kernel<<<BATCH, NMS_T, 0, stream>>>(deltas, priors, cnt, hcnt,
                                            segA, hotA, ovfA, hovA, out);
}